// Round 16
// baseline (170.292 us; speedup 1.0000x reference)
//
#include <hip/hip_runtime.h>
#include <math.h>

#define B 1024
#define E 256
#define H 4
#define DH 64
#define L 192
#define NF 16384
#define NO 49152
#define BPB 4    // batches per block
#define EP 264   // padded YZ row stride (floats): conflict-free h-banks
#define SP 200   // padded score row stride

// ---------------------------------------------------------------------------
// Kernel 0 (prep): blocks 0..191 transpose Wq, Wv, Wo into WT (WT[j][o]=W[o][j]);
// blocks 192..196 compute per-batch start offsets by binary search.
// ---------------------------------------------------------------------------
__global__ __launch_bounds__(256) void prep_kernel(
    const int* __restrict__ fb, const int* __restrict__ ob,
    int* __restrict__ start_f, int* __restrict__ start_o,
    const float* __restrict__ ipw, const float* __restrict__ opw,
    float* __restrict__ WT)
{
  int blk = blockIdx.x;
  if (blk < 192) {
    int m = blk / 64;                 // 0=Wq, 1=Wv, 2=Wo
    int r = blk % 64;
    int bx = (r & 7) * 32, by = (r >> 3) * 32;
    const float* src = (m == 0) ? ipw : (m == 1 ? ipw + 2 * E * E : opw);
    float* dst = WT + (size_t)m * E * E;
    __shared__ float tile[32][33];
    int tx = threadIdx.x & 31, ty = threadIdx.x >> 5;   // 32 x 8
#pragma unroll
    for (int i = 0; i < 32; i += 8)
      tile[ty + i][tx] = src[(size_t)(by + ty + i) * E + bx + tx];
    __syncthreads();
#pragma unroll
    for (int i = 0; i < 32; i += 8)
      dst[(size_t)(bx + ty + i) * E + by + tx] = tile[tx][ty + i];
  } else {
    int b = (blk - 192) * 256 + threadIdx.x;
    if (b > B) return;
    int lo = 0, hi = NF;
    while (lo < hi) { int m = (lo + hi) >> 1; if (fb[m] < b) lo = m + 1; else hi = m; }
    start_f[b] = lo;
    lo = 0; hi = NO;
    while (lo < hi) { int m = (lo + hi) >> 1; if (ob[m] < b) lo = m + 1; else hi = m; }
    start_o[b] = lo;
  }
}

// ---------------------------------------------------------------------------
// Fused kernel: 4 batches/block, 1024 threads (16 waves), grid 256.
//  q/ctx/out : wave -> (batch, j-quarter), float4 weight loads, 4-way LDS merge
//  Y         : wave -> (batch, head), direct
//  scores    : 4-lane groups per row, interleaved dims, 2-shfl reduce
//  softmax   : wave -> (batch, head), one butterfly per head
//  Z         : wave -> (batch, head), zero shuffles, no merge
// LDS ~58 KB.
// ---------------------------------------------------------------------------
__global__ __launch_bounds__(1024, 4) void fused_kernel(
    const float* __restrict__ scene,
    const float* __restrict__ face, const float* __restrict__ obj,
    const float* __restrict__ ipw, const float* __restrict__ ipb,
    const float* __restrict__ WqT, const float* __restrict__ WvT,
    const float* __restrict__ WoT, const float* __restrict__ opb,
    const float* __restrict__ gamma, const float* __restrict__ beta,
    const int* __restrict__ start_f, const int* __restrict__ start_o,
    float* __restrict__ fusedO, float* __restrict__ attnw)
{
  int b0 = blockIdx.x * BPB;
  int t = threadIdx.x, wave = t >> 6, lane = t & 63;

  __shared__ float sc_s[BPB][E];          // 4 KB
  __shared__ float q_s[BPB][E];           // 4 KB (reused as x)
  __shared__ float YZ_s[BPB][H][EP];      // 16.5 KB (Y, then Z), padded
  __shared__ float ctx_s[BPB][E];         // 4 KB
  __shared__ float s_s[BPB][H][SP];       // 12.8 KB scores -> softmax weights
  __shared__ float part_s[4][BPB][E];     // 16 KB weight-phase partials
  __shared__ float sb_s[BPB][H];
  __shared__ int   info_s[BPB][4];        // sf0, so0, n_f, n

  if (t < BPB * E) ((float*)sc_s)[t] = scene[(size_t)b0 * E + t];
  if (t < BPB) {
    int b = b0 + t;
    int sf0 = start_f[b], cf = start_f[b + 1] - sf0;
    int so0 = start_o[b], co = start_o[b + 1] - so0;
    info_s[t][0] = sf0; info_s[t][1] = so0;
    info_s[t][2] = min(cf, L); info_s[t][3] = min(cf + co, L);
  }
  __syncthreads();

  int bw = wave >> 2, sub = wave & 3;     // (batch, quarter/head/sub-id)

  // ---- q: wave (bw, jq=sub); lane owns outputs 4l..4l+3; j in [64jq,64jq+64)
  {
    const float4* W4 = (const float4*)WqT + lane;
    const float* sc = sc_s[bw];
    float4 a = {0.f, 0.f, 0.f, 0.f};
    int j0 = sub * 64;
#pragma unroll 8
    for (int jj = 0; jj < 64; ++jj) {
      int j = j0 + jj;
      float4 w = W4[(size_t)j * 64];
      float s = sc[j];
      a.x += s * w.x; a.y += s * w.y; a.z += s * w.z; a.w += s * w.w;
    }
    *(float4*)&part_s[sub][bw][4 * lane] = a;
  }
  __syncthreads();
  {
    int bi = t >> 8, e = t & 255;        // 1024 threads == BPB*E
    q_s[bi][e] = part_s[0][bi][e] + part_s[1][bi][e] +
                 part_s[2][bi][e] + part_s[3][bi][e] + ipb[e];
  }
  __syncthreads();

  // ---- sb (waves 0..3) + Y (all 16 waves: (bw, h=sub))
  if (wave < BPB) {
#pragma unroll
    for (int h = 0; h < H; ++h) {
      float v = q_s[wave][h * DH + lane] * ipb[E + h * DH + lane];
#pragma unroll
      for (int o = 32; o; o >>= 1) v += __shfl_xor(v, o);
      if (lane == 0) sb_s[wave][h] = v;
    }
  }
  {
    const float* Wk = ipw + (size_t)E * E;
    float4 a = {0.f, 0.f, 0.f, 0.f};
#pragma unroll 8
    for (int d = 0; d < DH; ++d) {
      float qv = q_s[bw][sub * DH + d];
      float4 w = *((const float4*)(Wk + (size_t)(sub * DH + d) * E) + lane);
      a.x += qv * w.x; a.y += qv * w.y; a.z += qv * w.z; a.w += qv * w.w;
    }
    *(float4*)&YZ_s[bw][sub][4 * lane] = a;
  }
  __syncthreads();

  int sf0 = info_s[bw][0], so0 = info_s[bw][1];
  int n_f = info_s[bw][2], n = info_s[bw][3];

  // ---- pass 1: scores. 4-lane group g owns a row; lane qd -> float4s qd+4k
  {
    int g = lane >> 2, qd = lane & 3;
    for (int s = sub * 16 + g; s < n; s += 64) {
      const float* xrow = (s < n_f) ? face + (size_t)(sf0 + s) * E
                                    : obj  + (size_t)(so0 + s - n_f) * E;
      const float4* xr = (const float4*)xrow;
      float p0 = 0.f, p1 = 0.f, p2 = 0.f, p3 = 0.f;
#pragma unroll
      for (int k = 0; k < 16; ++k) {
        int f = qd + 4 * k;
        float4 x4 = xr[f];
        int di = 4 * f;
        float4 y0 = *(const float4*)&YZ_s[bw][0][di];
        float4 y1 = *(const float4*)&YZ_s[bw][1][di];
        float4 y2 = *(const float4*)&YZ_s[bw][2][di];
        float4 y3 = *(const float4*)&YZ_s[bw][3][di];
        p0 += x4.x*y0.x + x4.y*y0.y + x4.z*y0.z + x4.w*y0.w;
        p1 += x4.x*y1.x + x4.y*y1.y + x4.z*y1.z + x4.w*y1.w;
        p2 += x4.x*y2.x + x4.y*y2.y + x4.z*y2.z + x4.w*y2.w;
        p3 += x4.x*y3.x + x4.y*y3.y + x4.z*y3.z + x4.w*y3.w;
      }
      p0 += __shfl_xor(p0, 1); p0 += __shfl_xor(p0, 2);
      p1 += __shfl_xor(p1, 1); p1 += __shfl_xor(p1, 2);
      p2 += __shfl_xor(p2, 1); p2 += __shfl_xor(p2, 2);
      p3 += __shfl_xor(p3, 1); p3 += __shfl_xor(p3, 2);
      float pv = (qd == 0) ? p0 : (qd == 1) ? p1 : (qd == 2) ? p2 : p3;
      s_s[bw][qd][s] = (pv + sb_s[bw][qd]) * 0.125f;
    }
  }
  __syncthreads();

  // ---- softmax: wave (bw, h=sub); normalize s_s in place
  if (n > 0) {
    float m = -3.0e38f;
    for (int s = lane; s < n; s += 64) m = fmaxf(m, s_s[bw][sub][s]);
#pragma unroll
    for (int o = 32; o; o >>= 1) m = fmaxf(m, __shfl_xor(m, o));
    float sum = 0.f;
    for (int s = lane; s < n; s += 64) {
      float e = __expf(s_s[bw][sub][s] - m);
      s_s[bw][sub][s] = e;
      sum += e;
    }
#pragma unroll
    for (int o = 32; o; o >>= 1) sum += __shfl_xor(sum, o);
    float inv = 1.0f / sum;
    for (int s = lane; s < n; s += 64) s_s[bw][sub][s] *= inv;
  }
  __syncthreads();

  // ---- attnw (768 <= 1024 threads)
  if (t < BPB * L) {
    int bi = t / L, s = t - bi * L;
    int nn = info_s[bi][3];
    float v;
    if (nn == 0) v = 1.0f / L;
    else if (s < nn)
      v = 0.25f * (s_s[bi][0][s] + s_s[bi][1][s] + s_s[bi][2][s] + s_s[bi][3][s]);
    else v = 0.f;
    attnw[(size_t)(b0 + bi) * L + s] = v;
  }

  // ---- pass 2: Z. wave (bw, h=sub); lane owns dims 4l..4l+3; no shuffles.
  {
    float4 z = {0.f, 0.f, 0.f, 0.f};
    float4 x4 = {0,0,0,0}; float w = 0.f;
    if (n > 0) {
      const float* xrow = (0 < n_f) ? face + (size_t)sf0 * E
                                    : obj  + (size_t)so0 * E;
      x4 = ((const float4*)xrow)[lane];
      w = s_s[bw][sub][0];
    }
    for (int s = 0; s < n; ++s) {
      float4 xn = {0,0,0,0}; float wn = 0.f;
      int sn = s + 1;
      if (sn < n) {
        const float* xrow = (sn < n_f) ? face + (size_t)(sf0 + sn) * E
                                       : obj  + (size_t)(so0 + sn - n_f) * E;
        xn = ((const float4*)xrow)[lane];
        wn = s_s[bw][sub][sn];
      }
      z.x += w * x4.x; z.y += w * x4.y; z.z += w * x4.z; z.w += w * x4.w;
      x4 = xn; w = wn;
    }
    *(float4*)&YZ_s[bw][sub][4 * lane] = z;   // overwrite Y with Z
  }
  __syncthreads();

  // ---- ctx: wave (bw, jq=sub); head(outputs 4l..) = l>>4
  {
    const float4* W4 = (const float4*)WvT + lane;
    const float* zr = YZ_s[bw][lane >> 4];
    float4 a = {0.f, 0.f, 0.f, 0.f};
    int j0 = sub * 64;
#pragma unroll 8
    for (int jj = 0; jj < 64; ++jj) {
      int j = j0 + jj;
      float4 w = W4[(size_t)j * 64];
      float zv = zr[j];
      a.x += zv * w.x; a.y += zv * w.y; a.z += zv * w.z; a.w += zv * w.w;
    }
    *(float4*)&part_s[sub][bw][4 * lane] = a;
  }
  __syncthreads();
  {
    int bi = t >> 8, e = t & 255;
    ctx_s[bi][e] = part_s[0][bi][e] + part_s[1][bi][e] +
                   part_s[2][bi][e] + part_s[3][bi][e] + ipb[2 * E + e];
  }
  __syncthreads();

  // ---- out-proj
  {
    const float4* W4 = (const float4*)WoT + lane;
    const float* cr = ctx_s[bw];
    float4 a = {0.f, 0.f, 0.f, 0.f};
    int j0 = sub * 64;
#pragma unroll 8
    for (int jj = 0; jj < 64; ++jj) {
      int j = j0 + jj;
      float4 w = W4[(size_t)j * 64];
      float cv = cr[j];
      a.x += cv * w.x; a.y += cv * w.y; a.z += cv * w.z; a.w += cv * w.w;
    }
    *(float4*)&part_s[sub][bw][4 * lane] = a;
  }
  __syncthreads();
  {
    int bi = t >> 8, e = t & 255;
    q_s[bi][e] = part_s[0][bi][e] + part_s[1][bi][e] +
                 part_s[2][bi][e] + part_s[3][bi][e] + opb[e] + sc_s[bi][e];
  }
  __syncthreads();

  // ---- LayerNorm: waves 0..3, one batch each
  if (wave < BPB) {
    float v0 = q_s[wave][lane], v1 = q_s[wave][lane + 64],
          v2 = q_s[wave][lane + 128], v3 = q_s[wave][lane + 192];
    float s1 = v0 + v1 + v2 + v3;
#pragma unroll
    for (int o = 32; o; o >>= 1) s1 += __shfl_xor(s1, o);
    float mu = s1 * (1.0f / E);
    float d0 = v0 - mu, d1 = v1 - mu, d2 = v2 - mu, d3 = v3 - mu;
    float s2 = d0*d0 + d1*d1 + d2*d2 + d3*d3;
#pragma unroll
    for (int o = 32; o; o >>= 1) s2 += __shfl_xor(s2, o);
    float inv = 1.0f / sqrtf(s2 * (1.0f / E) + 1e-5f);
    size_t base = (size_t)(b0 + wave) * E;
    fusedO[base + lane      ] = d0 * inv * gamma[lane      ] + beta[lane      ];
    fusedO[base + lane +  64] = d1 * inv * gamma[lane +  64] + beta[lane +  64];
    fusedO[base + lane + 128] = d2 * inv * gamma[lane + 128] + beta[lane + 128];
    fusedO[base + lane + 192] = d3 * inv * gamma[lane + 192] + beta[lane + 192];
  }
}

// ---------------------------------------------------------------------------
extern "C" void kernel_launch(void* const* d_in, const int* in_sizes, int n_in,
                              void* d_out, int out_size, void* d_ws, size_t ws_size,
                              hipStream_t stream) {
  const float* scene = (const float*)d_in[0];
  const float* face  = (const float*)d_in[1];
  const float* obj   = (const float*)d_in[2];
  const int*   fb    = (const int*)d_in[3];
  const int*   ob    = (const int*)d_in[4];
  const float* ipw   = (const float*)d_in[5];
  const float* ipb   = (const float*)d_in[6];
  const float* opw   = (const float*)d_in[7];
  const float* opb   = (const float*)d_in[8];
  const float* gam   = (const float*)d_in[9];
  const float* bet   = (const float*)d_in[10];

  float* fused = (float*)d_out;
  float* attnw = fused + (size_t)B * E;

  // ws: starts (16KB) | WT (768KB)
  int* start_f = (int*)d_ws;
  int* start_o = start_f + (B + 1);
  float* WT   = (float*)((char*)d_ws + (16 << 10));
  float* WqT = WT;
  float* WvT = WT + (size_t)E * E;
  float* WoT = WT + (size_t)2 * E * E;

  prep_kernel<<<197, 256, 0, stream>>>(fb, ob, start_f, start_o, ipw, opw, WT);
  fused_kernel<<<B / BPB, 1024, 0, stream>>>(scene, face, obj, ipw, ipb,
                                             WqT, WvT, WoT, opb, gam, bet,
                                             start_f, start_o, fused, attnw);
}

// Round 17
// 66.211 us; speedup vs baseline: 2.5720x; 2.5720x over previous
//
#include <hip/hip_runtime.h>
#include <math.h>

#define B 1024
#define E 256
#define H 4
#define DH 64
#define L 192
#define NF 16384
#define NO 49152
#define BPB 4   // batches per block

// ---------------------------------------------------------------------------
// Kernel 0 (prep): blocks 0..191 transpose Wq, Wv, Wo into WT (WT[j][o]=W[o][j]);
// blocks 192..196 compute per-batch start offsets by binary search.
// ---------------------------------------------------------------------------
__global__ __launch_bounds__(256) void prep_kernel(
    const int* __restrict__ fb, const int* __restrict__ ob,
    int* __restrict__ start_f, int* __restrict__ start_o,
    const float* __restrict__ ipw, const float* __restrict__ opw,
    float* __restrict__ WT)
{
  int blk = blockIdx.x;
  if (blk < 192) {
    int m = blk / 64;                 // 0=Wq, 1=Wv, 2=Wo
    int r = blk % 64;
    int bx = (r & 7) * 32, by = (r >> 3) * 32;
    const float* src = (m == 0) ? ipw : (m == 1 ? ipw + 2 * E * E : opw);
    float* dst = WT + (size_t)m * E * E;
    __shared__ float tile[32][33];
    int tx = threadIdx.x & 31, ty = threadIdx.x >> 5;   // 32 x 8
#pragma unroll
    for (int i = 0; i < 32; i += 8)
      tile[ty + i][tx] = src[(size_t)(by + ty + i) * E + bx + tx];
    __syncthreads();
#pragma unroll
    for (int i = 0; i < 32; i += 8)
      dst[(size_t)(bx + ty + i) * E + by + tx] = tile[tx][ty + i];
  } else {
    int b = (blk - 192) * 256 + threadIdx.x;
    if (b > B) return;
    int lo = 0, hi = NF;
    while (lo < hi) { int m = (lo + hi) >> 1; if (fb[m] < b) lo = m + 1; else hi = m; }
    start_f[b] = lo;
    lo = 0; hi = NO;
    while (lo < hi) { int m = (lo + hi) >> 1; if (ob[m] < b) lo = m + 1; else hi = m; }
    start_o[b] = lo;
  }
}

// ---------------------------------------------------------------------------
// Fused kernel: 4 batches/block, 512 threads (8 waves), grid 256.
// Identical to the proven 71.3us version EXCEPT the X-stream processes 2 rows
// per iteration with dual prefetch (4 outstanding loads, 8-wide shfl ILP).
// ---------------------------------------------------------------------------
__global__ __launch_bounds__(512) void fused_kernel(
    const float* __restrict__ scene,
    const float* __restrict__ face, const float* __restrict__ obj,
    const float* __restrict__ ipw, const float* __restrict__ ipb,
    const float* __restrict__ WqT, const float* __restrict__ WvT,
    const float* __restrict__ WoT, const float* __restrict__ opb,
    const float* __restrict__ gamma, const float* __restrict__ beta,
    const int* __restrict__ start_f, const int* __restrict__ start_o,
    float* __restrict__ fusedO, float* __restrict__ attnw)
{
  int b0 = blockIdx.x * BPB;
  int t = threadIdx.x, wave = t >> 6, lane = t & 63;

  __shared__ float sc_s[BPB][E];        // 4 KB   scene rows
  __shared__ float q_s[BPB][E];         // 4 KB   q; reused later for x
  __shared__ float Y_s[BPB][H][E];      // 16 KB
  __shared__ float Z_s[BPB][H][E];      // 16 KB
  __shared__ float ctx_s[BPB][E];       // 4 KB
  __shared__ float s_s[BPB][H][L];      // 12 KB  raw scores
  __shared__ float part_s[8][BPB][E];   // 32 KB  per-wave partials (multi-use)
  __shared__ float Zp_s[BPB][2][H][E];  // 32 KB  per-wave-half Z partials
  __shared__ float mw_s[BPB][2][H], su_s[BPB][2][H], sb_s[BPB][H];
  __shared__ int   info_s[BPB][4];      // sf0, so0, n_f, n

  for (int i = t; i < BPB * E; i += 512)
    ((float*)sc_s)[i] = scene[(size_t)b0 * E + i];
  if (t < BPB) {
    int b = b0 + t;
    int sf0 = start_f[b], cf = start_f[b + 1] - sf0;
    int so0 = start_o[b], co = start_o[b + 1] - so0;
    info_s[t][0] = sf0; info_s[t][1] = so0;
    info_s[t][2] = min(cf, L); info_s[t][3] = min(cf + co, L);
  }
  __syncthreads();

  // ---- q partials: wave covers j in [32*wave, 32*wave+32); lane owns 4 outs
  {
    const float4* W4 = (const float4*)WqT + lane;
    float4 a0 = {0,0,0,0}, a1 = {0,0,0,0}, a2 = {0,0,0,0}, a3 = {0,0,0,0};
    int j0 = wave * 32;
#pragma unroll
    for (int jj = 0; jj < 32; ++jj) {
      int j = j0 + jj;
      float4 w = W4[(size_t)j * 64];
      float s0 = sc_s[0][j], s1 = sc_s[1][j], s2 = sc_s[2][j], s3 = sc_s[3][j];
      a0.x += s0*w.x; a0.y += s0*w.y; a0.z += s0*w.z; a0.w += s0*w.w;
      a1.x += s1*w.x; a1.y += s1*w.y; a1.z += s1*w.z; a1.w += s1*w.w;
      a2.x += s2*w.x; a2.y += s2*w.y; a2.z += s2*w.z; a2.w += s2*w.w;
      a3.x += s3*w.x; a3.y += s3*w.y; a3.z += s3*w.z; a3.w += s3*w.w;
    }
    *(float4*)&part_s[wave][0][4 * lane] = a0;
    *(float4*)&part_s[wave][1][4 * lane] = a1;
    *(float4*)&part_s[wave][2][4 * lane] = a2;
    *(float4*)&part_s[wave][3][4 * lane] = a3;
  }
  __syncthreads();
  for (int i = t; i < BPB * E; i += 512) {
    int bi = i >> 8, e = i & 255;
    float v = ipb[e];
#pragma unroll
    for (int w = 0; w < 8; ++w) v += part_s[w][bi][e];
    q_s[bi][e] = v;
  }
  __syncthreads();

  // ---- sb[b][h] = q_h · bk_h  (waves 0..3, one batch each)
  if (wave < BPB) {
#pragma unroll
    for (int h = 0; h < H; ++h) {
      float v = q_s[wave][h * DH + lane] * ipb[E + h * DH + lane];
#pragma unroll
      for (int o = 32; o; o >>= 1) v += __shfl_xor(v, o);
      if (lane == 0) sb_s[wave][h] = v;
    }
  }

  // ---- Y partials: wave -> (h = wave>>1, d-range = (wave&1)*32)
  {
    const float* Wk = ipw + (size_t)E * E;
    int h = wave >> 1, d0 = (wave & 1) * 32;
    float4 a0 = {0,0,0,0}, a1 = {0,0,0,0}, a2 = {0,0,0,0}, a3 = {0,0,0,0};
#pragma unroll
    for (int dd = 0; dd < 32; ++dd) {
      int d = d0 + dd;
      float4 w = *((const float4*)(Wk + (size_t)(h * DH + d) * E) + lane);
      float q0 = q_s[0][h * DH + d], q1 = q_s[1][h * DH + d];
      float q2 = q_s[2][h * DH + d], q3 = q_s[3][h * DH + d];
      a0.x += q0*w.x; a0.y += q0*w.y; a0.z += q0*w.z; a0.w += q0*w.w;
      a1.x += q1*w.x; a1.y += q1*w.y; a1.z += q1*w.z; a1.w += q1*w.w;
      a2.x += q2*w.x; a2.y += q2*w.y; a2.z += q2*w.z; a2.w += q2*w.w;
      a3.x += q3*w.x; a3.y += q3*w.y; a3.z += q3*w.z; a3.w += q3*w.w;
    }
    // alias part_s as Yp[wi][bi][h][e]
    float* Yp = (float*)part_s;
    int wi = wave & 1;
    size_t o0 = (((size_t)wi * BPB + 0) * H + h) * E + 4 * lane;
    size_t o1 = (((size_t)wi * BPB + 1) * H + h) * E + 4 * lane;
    size_t o2 = (((size_t)wi * BPB + 2) * H + h) * E + 4 * lane;
    size_t o3 = (((size_t)wi * BPB + 3) * H + h) * E + 4 * lane;
    *(float4*)&Yp[o0] = a0; *(float4*)&Yp[o1] = a1;
    *(float4*)&Yp[o2] = a2; *(float4*)&Yp[o3] = a3;
  }
  __syncthreads();
  {
    float* Yp = (float*)part_s;
    for (int i = t; i < BPB * H * E; i += 512)
      ((float*)Y_s)[i] = Yp[i] + Yp[BPB * H * E + i];
  }
  __syncthreads();

  // ---- X-stream phase: 2 waves per batch (bb = wave>>1, wi = wave&1)
  //      2 rows per iteration (s, s+2), dual prefetch (s+4, s+6)
  {
    int bb = wave >> 1, wi = wave & 1;
    int sf0 = info_s[bb][0], so0 = info_s[bb][1];
    int n_f = info_s[bb][2], n = info_s[bb][3];

    float4 y0 = *(const float4*)&Y_s[bb][0][4 * lane];
    float4 y1 = *(const float4*)&Y_s[bb][1][4 * lane];
    float4 y2 = *(const float4*)&Y_s[bb][2][4 * lane];
    float4 y3 = *(const float4*)&Y_s[bb][3][4 * lane];
    float sb0 = sb_s[bb][0], sb1 = sb_s[bb][1], sb2 = sb_s[bb][2], sb3 = sb_s[bb][3];

    float m0 = -3.0e38f, m1 = -3.0e38f, m2 = -3.0e38f, m3 = -3.0e38f;
    float u0 = 0.f, u1 = 0.f, u2 = 0.f, u3 = 0.f;
    float4 acc0 = {0,0,0,0}, acc1 = {0,0,0,0}, acc2 = {0,0,0,0}, acc3 = {0,0,0,0};

    float4 xa = {0,0,0,0}, xb = {0,0,0,0};
    if (wi < n) {
      const float* xr = (wi < n_f) ? face + (size_t)(sf0 + wi) * E
                                   : obj  + (size_t)(so0 + wi - n_f) * E;
      xa = ((const float4*)xr)[lane];
    }
    if (wi + 2 < n) {
      int s2 = wi + 2;
      const float* xr = (s2 < n_f) ? face + (size_t)(sf0 + s2) * E
                                   : obj  + (size_t)(so0 + s2 - n_f) * E;
      xb = ((const float4*)xr)[lane];
    }

    for (int s = wi; s < n; s += 4) {
      int s2 = s + 2;
      // prefetch next pair
      float4 xna = {0,0,0,0}, xnb = {0,0,0,0};
      if (s + 4 < n) {
        int sn = s + 4;
        const float* xr = (sn < n_f) ? face + (size_t)(sf0 + sn) * E
                                     : obj  + (size_t)(so0 + sn - n_f) * E;
        xna = ((const float4*)xr)[lane];
      }
      if (s + 6 < n) {
        int sn = s + 6;
        const float* xr = (sn < n_f) ? face + (size_t)(sf0 + sn) * E
                                     : obj  + (size_t)(so0 + sn - n_f) * E;
        xnb = ((const float4*)xr)[lane];
      }

      float pa0 = xa.x*y0.x + xa.y*y0.y + xa.z*y0.z + xa.w*y0.w;
      float pa1 = xa.x*y1.x + xa.y*y1.y + xa.z*y1.z + xa.w*y1.w;
      float pa2 = xa.x*y2.x + xa.y*y2.y + xa.z*y2.z + xa.w*y2.w;
      float pa3 = xa.x*y3.x + xa.y*y3.y + xa.z*y3.z + xa.w*y3.w;
      float pb0 = xb.x*y0.x + xb.y*y0.y + xb.z*y0.z + xb.w*y0.w;
      float pb1 = xb.x*y1.x + xb.y*y1.y + xb.z*y1.z + xb.w*y1.w;
      float pb2 = xb.x*y2.x + xb.y*y2.y + xb.z*y2.z + xb.w*y2.w;
      float pb3 = xb.x*y3.x + xb.y*y3.y + xb.z*y3.z + xb.w*y3.w;
#pragma unroll
      for (int o = 32; o; o >>= 1) {
        pa0 += __shfl_xor(pa0, o); pa1 += __shfl_xor(pa1, o);
        pa2 += __shfl_xor(pa2, o); pa3 += __shfl_xor(pa3, o);
        pb0 += __shfl_xor(pb0, o); pb1 += __shfl_xor(pb1, o);
        pb2 += __shfl_xor(pb2, o); pb3 += __shfl_xor(pb3, o);
      }
      pa0 = (pa0 + sb0) * 0.125f; pa1 = (pa1 + sb1) * 0.125f;
      pa2 = (pa2 + sb2) * 0.125f; pa3 = (pa3 + sb3) * 0.125f;
      pb0 = (pb0 + sb0) * 0.125f; pb1 = (pb1 + sb1) * 0.125f;
      pb2 = (pb2 + sb2) * 0.125f; pb3 = (pb3 + sb3) * 0.125f;
      if (lane == 0) {
        s_s[bb][0][s] = pa0; s_s[bb][1][s] = pa1;
        s_s[bb][2][s] = pa2; s_s[bb][3][s] = pa3;
        if (s2 < n) {
          s_s[bb][0][s2] = pb0; s_s[bb][1][s2] = pb1;
          s_s[bb][2][s2] = pb2; s_s[bb][3][s2] = pb3;
        }
      }
      // online update row s
      if (pa0 > m0) {
        float f = __expf(m0 - pa0);
        acc0.x = acc0.x*f + xa.x; acc0.y = acc0.y*f + xa.y;
        acc0.z = acc0.z*f + xa.z; acc0.w = acc0.w*f + xa.w;
        u0 = u0*f + 1.f; m0 = pa0;
      } else {
        float e = __expf(pa0 - m0);
        acc0.x += e*xa.x; acc0.y += e*xa.y; acc0.z += e*xa.z; acc0.w += e*xa.w;
        u0 += e;
      }
      if (pa1 > m1) {
        float f = __expf(m1 - pa1);
        acc1.x = acc1.x*f + xa.x; acc1.y = acc1.y*f + xa.y;
        acc1.z = acc1.z*f + xa.z; acc1.w = acc1.w*f + xa.w;
        u1 = u1*f + 1.f; m1 = pa1;
      } else {
        float e = __expf(pa1 - m1);
        acc1.x += e*xa.x; acc1.y += e*xa.y; acc1.z += e*xa.z; acc1.w += e*xa.w;
        u1 += e;
      }
      if (pa2 > m2) {
        float f = __expf(m2 - pa2);
        acc2.x = acc2.x*f + xa.x; acc2.y = acc2.y*f + xa.y;
        acc2.z = acc2.z*f + xa.z; acc2.w = acc2.w*f + xa.w;
        u2 = u2*f + 1.f; m2 = pa2;
      } else {
        float e = __expf(pa2 - m2);
        acc2.x += e*xa.x; acc2.y += e*xa.y; acc2.z += e*xa.z; acc2.w += e*xa.w;
        u2 += e;
      }
      if (pa3 > m3) {
        float f = __expf(m3 - pa3);
        acc3.x = acc3.x*f + xa.x; acc3.y = acc3.y*f + xa.y;
        acc3.z = acc3.z*f + xa.z; acc3.w = acc3.w*f + xa.w;
        u3 = u3*f + 1.f; m3 = pa3;
      } else {
        float e = __expf(pa3 - m3);
        acc3.x += e*xa.x; acc3.y += e*xa.y; acc3.z += e*xa.z; acc3.w += e*xa.w;
        u3 += e;
      }
      // online update row s+2
      if (s2 < n) {
        if (pb0 > m0) {
          float f = __expf(m0 - pb0);
          acc0.x = acc0.x*f + xb.x; acc0.y = acc0.y*f + xb.y;
          acc0.z = acc0.z*f + xb.z; acc0.w = acc0.w*f + xb.w;
          u0 = u0*f + 1.f; m0 = pb0;
        } else {
          float e = __expf(pb0 - m0);
          acc0.x += e*xb.x; acc0.y += e*xb.y; acc0.z += e*xb.z; acc0.w += e*xb.w;
          u0 += e;
        }
        if (pb1 > m1) {
          float f = __expf(m1 - pb1);
          acc1.x = acc1.x*f + xb.x; acc1.y = acc1.y*f + xb.y;
          acc1.z = acc1.z*f + xb.z; acc1.w = acc1.w*f + xb.w;
          u1 = u1*f + 1.f; m1 = pb1;
        } else {
          float e = __expf(pb1 - m1);
          acc1.x += e*xb.x; acc1.y += e*xb.y; acc1.z += e*xb.z; acc1.w += e*xb.w;
          u1 += e;
        }
        if (pb2 > m2) {
          float f = __expf(m2 - pb2);
          acc2.x = acc2.x*f + xb.x; acc2.y = acc2.y*f + xb.y;
          acc2.z = acc2.z*f + xb.z; acc2.w = acc2.w*f + xb.w;
          u2 = u2*f + 1.f; m2 = pb2;
        } else {
          float e = __expf(pb2 - m2);
          acc2.x += e*xb.x; acc2.y += e*xb.y; acc2.z += e*xb.z; acc2.w += e*xb.w;
          u2 += e;
        }
        if (pb3 > m3) {
          float f = __expf(m3 - pb3);
          acc3.x = acc3.x*f + xb.x; acc3.y = acc3.y*f + xb.y;
          acc3.z = acc3.z*f + xb.z; acc3.w = acc3.w*f + xb.w;
          u3 = u3*f + 1.f; m3 = pb3;
        } else {
          float e = __expf(pb3 - m3);
          acc3.x += e*xb.x; acc3.y += e*xb.y; acc3.z += e*xb.z; acc3.w += e*xb.w;
          u3 += e;
        }
      }
      xa = xna; xb = xnb;
    }
    *(float4*)&Zp_s[bb][wi][0][4 * lane] = acc0;
    *(float4*)&Zp_s[bb][wi][1][4 * lane] = acc1;
    *(float4*)&Zp_s[bb][wi][2][4 * lane] = acc2;
    *(float4*)&Zp_s[bb][wi][3][4 * lane] = acc3;
    if (lane == 0) {
      mw_s[bb][wi][0] = m0; mw_s[bb][wi][1] = m1;
      mw_s[bb][wi][2] = m2; mw_s[bb][wi][3] = m3;
      su_s[bb][wi][0] = u0; su_s[bb][wi][1] = u1;
      su_s[bb][wi][2] = u2; su_s[bb][wi][3] = u3;
    }
  }
  __syncthreads();

  // ---- merge Z (2 halves) ; normalize
  for (int i = t; i < BPB * H * E; i += 512) {
    int bi = i >> 10, rem = i & 1023, h = rem >> 8, e = rem & 255;
    float z = 0.f;
    if (info_s[bi][3] > 0) {
      float ma = mw_s[bi][0][h], mb = mw_s[bi][1][h];
      float M = fmaxf(ma, mb);
      float fa = __expf(ma - M), fb = __expf(mb - M);
      float inv = 1.0f / (fa * su_s[bi][0][h] + fb * su_s[bi][1][h]);
      z = (fa * Zp_s[bi][0][h][e] + fb * Zp_s[bi][1][h][e]) * inv;
    }
    ((float*)Z_s)[i] = z;
  }
  // ---- attnw
  for (int i = t; i < BPB * L; i += 512) {
    int bi = i / L, s = i - bi * L;
    int n = info_s[bi][3];
    float v;
    if (n == 0) v = 1.0f / L;
    else if (s < n) {
      v = 0.f;
#pragma unroll
      for (int h = 0; h < H; ++h) {
        float ma = mw_s[bi][0][h], mb = mw_s[bi][1][h];
        float M = fmaxf(ma, mb);
        float fa = __expf(ma - M), fb = __expf(mb - M);
        float inv = 1.0f / (fa * su_s[bi][0][h] + fb * su_s[bi][1][h]);
        v += __expf(s_s[bi][h][s] - M) * inv;
      }
      v *= 0.25f;
    } else v = 0.f;
    attnw[(size_t)(b0 + bi) * L + s] = v;
  }
  __syncthreads();

  // ---- ctx partials: wave covers j-range 32; head(lane) = lane>>4
  {
    const float4* W4 = (const float4*)WvT + lane;
    int j0 = wave * 32, hoff = (lane >> 4) * E;
    float4 a0 = {0,0,0,0}, a1 = {0,0,0,0}, a2 = {0,0,0,0}, a3 = {0,0,0,0};
#pragma unroll
    for (int jj = 0; jj < 32; ++jj) {
      int j = j0 + jj;
      float4 w = W4[(size_t)j * 64];
      float z0 = ((float*)Z_s[0])[hoff + j];
      float z1 = ((float*)Z_s[1])[hoff + j];
      float z2 = ((float*)Z_s[2])[hoff + j];
      float z3 = ((float*)Z_s[3])[hoff + j];
      a0.x += z0*w.x; a0.y += z0*w.y; a0.z += z0*w.z; a0.w += z0*w.w;
      a1.x += z1*w.x; a1.y += z1*w.y; a1.z += z1*w.z; a1.w += z1*w.w;
      a2.x += z2*w.x; a2.y += z2*w.y; a2.z += z2*w.z; a2.w += z2*w.w;
      a3.x += z3*w.x; a3.y += z3*w.y; a3.z += z3*w.z; a3.w += z3*w.w;
    }
    *(float4*)&part_s[wave][0][4 * lane] = a0;
    *(float4*)&part_s[wave][1][4 * lane] = a1;
    *(float4*)&part_s[wave][2][4 * lane] = a2;
    *(float4*)&part_s[wave][3][4 * lane] = a3;
  }
  __syncthreads();
  for (int i = t; i < BPB * E; i += 512) {
    int bi = i >> 8, e = i & 255;
    float v = ipb[2 * E + e];
#pragma unroll
    for (int w = 0; w < 8; ++w) v += part_s[w][bi][e];
    ctx_s[bi][e] = v;
  }
  __syncthreads();

  // ---- out-proj partials
  {
    const float4* W4 = (const float4*)WoT + lane;
    int j0 = wave * 32;
    float4 a0 = {0,0,0,0}, a1 = {0,0,0,0}, a2 = {0,0,0,0}, a3 = {0,0,0,0};
#pragma unroll
    for (int jj = 0; jj < 32; ++jj) {
      int j = j0 + jj;
      float4 w = W4[(size_t)j * 64];
      float c0 = ctx_s[0][j], c1 = ctx_s[1][j], c2 = ctx_s[2][j], c3 = ctx_s[3][j];
      a0.x += c0*w.x; a0.y += c0*w.y; a0.z += c0*w.z; a0.w += c0*w.w;
      a1.x += c1*w.x; a1.y += c1*w.y; a1.z += c1*w.z; a1.w += c1*w.w;
      a2.x += c2*w.x; a2.y += c2*w.y; a2.z += c2*w.z; a2.w += c2*w.w;
      a3.x += c3*w.x; a3.y += c3*w.y; a3.z += c3*w.z; a3.w += c3*w.w;
    }
    *(float4*)&part_s[wave][0][4 * lane] = a0;
    *(float4*)&part_s[wave][1][4 * lane] = a1;
    *(float4*)&part_s[wave][2][4 * lane] = a2;
    *(float4*)&part_s[wave][3][4 * lane] = a3;
  }
  __syncthreads();
  // x = Σ partials + opb + residual; store into q_s (reused as x_s)
  for (int i = t; i < BPB * E; i += 512) {
    int bi = i >> 8, e = i & 255;
    float v = opb[e] + sc_s[bi][e];
#pragma unroll
    for (int w = 0; w < 8; ++w) v += part_s[w][bi][e];
    q_s[bi][e] = v;
  }
  __syncthreads();

  // ---- LayerNorm: waves 0..3, one batch each (in-wave over 256 values)
  if (wave < BPB) {
    float v0 = q_s[wave][lane], v1 = q_s[wave][lane + 64],
          v2 = q_s[wave][lane + 128], v3 = q_s[wave][lane + 192];
    float s1 = v0 + v1 + v2 + v3;
#pragma unroll
    for (int o = 32; o; o >>= 1) s1 += __shfl_xor(s1, o);
    float mu = s1 * (1.0f / E);
    float d0 = v0 - mu, d1 = v1 - mu, d2 = v2 - mu, d3 = v3 - mu;
    float s2 = d0*d0 + d1*d1 + d2*d2 + d3*d3;
#pragma unroll
    for (int o = 32; o; o >>= 1) s2 += __shfl_xor(s2, o);
    float inv = 1.0f / sqrtf(s2 * (1.0f / E) + 1e-5f);
    size_t base = (size_t)(b0 + wave) * E;
    fusedO[base + lane      ] = d0 * inv * gamma[lane      ] + beta[lane      ];
    fusedO[base + lane +  64] = d1 * inv * gamma[lane +  64] + beta[lane +  64];
    fusedO[base + lane + 128] = d2 * inv * gamma[lane + 128] + beta[lane + 128];
    fusedO[base + lane + 192] = d3 * inv * gamma[lane + 192] + beta[lane + 192];
  }
}

// ---------------------------------------------------------------------------
extern "C" void kernel_launch(void* const* d_in, const int* in_sizes, int n_in,
                              void* d_out, int out_size, void* d_ws, size_t ws_size,
                              hipStream_t stream) {
  const float* scene = (const float*)d_in[0];
  const float* face  = (const float*)d_in[1];
  const float* obj   = (const float*)d_in[2];
  const int*   fb    = (const int*)d_in[3];
  const int*   ob    = (const int*)d_in[4];
  const float* ipw   = (const float*)d_in[5];
  const float* ipb   = (const float*)d_in[6];
  const float* opw   = (const float*)d_in[7];
  const float* opb   = (const float*)d_in[8];
  const float* gam   = (const float*)d_in[9];
  const float* bet   = (const float*)d_in[10];

  float* fused = (float*)d_out;
  float* attnw = fused + (size_t)B * E;

  // ws: starts (16KB) | WT (768KB)
  int* start_f = (int*)d_ws;
  int* start_o = start_f + (B + 1);
  float* WT   = (float*)((char*)d_ws + (16 << 10));
  float* WqT = WT;
  float* WvT = WT + (size_t)E * E;
  float* WoT = WT + (size_t)2 * E * E;

  prep_kernel<<<197, 256, 0, stream>>>(fb, ob, start_f, start_o, ipw, opw, WT);
  fused_kernel<<<B / BPB, 512, 0, stream>>>(scene, face, obj, ipw, ipb,
                                            WqT, WvT, WoT, opb, gam, bet,
                                            start_f, start_o, fused, attnw);
}

// Round 18
// 54.894 us; speedup vs baseline: 3.1022x; 1.2062x over previous
//
#include <hip/hip_runtime.h>
#include <math.h>

#define B 1024
#define E 256
#define H 4
#define DH 64
#define L 192
#define NF 16384
#define NO 49152
#define BPB 4   // batches per block

// ---------------------------------------------------------------------------
// Kernel 0 (prep): blocks 0..191 transpose Wq, Wv, Wo into WT (WT[j][o]=W[o][j]);
// blocks 192..196 compute per-batch start offsets by binary search.
// ---------------------------------------------------------------------------
__global__ __launch_bounds__(256) void prep_kernel(
    const int* __restrict__ fb, const int* __restrict__ ob,
    int* __restrict__ start_f, int* __restrict__ start_o,
    const float* __restrict__ ipw, const float* __restrict__ opw,
    float* __restrict__ WT)
{
  int blk = blockIdx.x;
  if (blk < 192) {
    int m = blk / 64;                 // 0=Wq, 1=Wv, 2=Wo
    int r = blk % 64;
    int bx = (r & 7) * 32, by = (r >> 3) * 32;
    const float* src = (m == 0) ? ipw : (m == 1 ? ipw + 2 * E * E : opw);
    float* dst = WT + (size_t)m * E * E;
    __shared__ float tile[32][33];
    int tx = threadIdx.x & 31, ty = threadIdx.x >> 5;   // 32 x 8
#pragma unroll
    for (int i = 0; i < 32; i += 8)
      tile[ty + i][tx] = src[(size_t)(by + ty + i) * E + bx + tx];
    __syncthreads();
#pragma unroll
    for (int i = 0; i < 32; i += 8)
      dst[(size_t)(bx + ty + i) * E + by + tx] = tile[tx][ty + i];
  } else {
    int b = (blk - 192) * 256 + threadIdx.x;
    if (b > B) return;
    int lo = 0, hi = NF;
    while (lo < hi) { int m = (lo + hi) >> 1; if (fb[m] < b) lo = m + 1; else hi = m; }
    start_f[b] = lo;
    lo = 0; hi = NO;
    while (lo < hi) { int m = (lo + hi) >> 1; if (ob[m] < b) lo = m + 1; else hi = m; }
    start_o[b] = lo;
  }
}

// ---------------------------------------------------------------------------
// Fused kernel: 4 batches/block, 512 threads (8 waves), grid 256.
// Same as the 66.2us version EXCEPT the X-stream uses 16-lane row groups:
// 4 rows/wave in flight, 4-level shfl reduce (24 -> 4 shfl per row), private
// per-group online softmax state merged in-register at the end.
// ---------------------------------------------------------------------------
__global__ __launch_bounds__(512, 2) void fused_kernel(
    const float* __restrict__ scene,
    const float* __restrict__ face, const float* __restrict__ obj,
    const float* __restrict__ ipw, const float* __restrict__ ipb,
    const float* __restrict__ WqT, const float* __restrict__ WvT,
    const float* __restrict__ WoT, const float* __restrict__ opb,
    const float* __restrict__ gamma, const float* __restrict__ beta,
    const int* __restrict__ start_f, const int* __restrict__ start_o,
    float* __restrict__ fusedO, float* __restrict__ attnw)
{
  int b0 = blockIdx.x * BPB;
  int t = threadIdx.x, wave = t >> 6, lane = t & 63;

  __shared__ float sc_s[BPB][E];        // 4 KB   scene rows
  __shared__ float q_s[BPB][E];         // 4 KB   q; reused later for x
  __shared__ float Y_s[BPB][H][E];      // 16 KB
  __shared__ float Z_s[BPB][H][E];      // 16 KB
  __shared__ float ctx_s[BPB][E];       // 4 KB
  __shared__ float s_s[BPB][H][L];      // 12 KB  raw scores
  __shared__ float part_s[8][BPB][E];   // 32 KB  per-wave partials (multi-use)
  __shared__ float Zp_s[BPB][2][H][E];  // 32 KB  per-wave Z partials
  __shared__ float mw_s[BPB][2][H], su_s[BPB][2][H], sb_s[BPB][H];
  __shared__ int   info_s[BPB][4];      // sf0, so0, n_f, n

  for (int i = t; i < BPB * E; i += 512)
    ((float*)sc_s)[i] = scene[(size_t)b0 * E + i];
  if (t < BPB) {
    int b = b0 + t;
    int sf0 = start_f[b], cf = start_f[b + 1] - sf0;
    int so0 = start_o[b], co = start_o[b + 1] - so0;
    info_s[t][0] = sf0; info_s[t][1] = so0;
    info_s[t][2] = min(cf, L); info_s[t][3] = min(cf + co, L);
  }
  __syncthreads();

  // ---- q partials: wave covers j in [32*wave, 32*wave+32); lane owns 4 outs
  {
    const float4* W4 = (const float4*)WqT + lane;
    float4 a0 = {0,0,0,0}, a1 = {0,0,0,0}, a2 = {0,0,0,0}, a3 = {0,0,0,0};
    int j0 = wave * 32;
#pragma unroll
    for (int jj = 0; jj < 32; ++jj) {
      int j = j0 + jj;
      float4 w = W4[(size_t)j * 64];
      float s0 = sc_s[0][j], s1 = sc_s[1][j], s2 = sc_s[2][j], s3 = sc_s[3][j];
      a0.x += s0*w.x; a0.y += s0*w.y; a0.z += s0*w.z; a0.w += s0*w.w;
      a1.x += s1*w.x; a1.y += s1*w.y; a1.z += s1*w.z; a1.w += s1*w.w;
      a2.x += s2*w.x; a2.y += s2*w.y; a2.z += s2*w.z; a2.w += s2*w.w;
      a3.x += s3*w.x; a3.y += s3*w.y; a3.z += s3*w.z; a3.w += s3*w.w;
    }
    *(float4*)&part_s[wave][0][4 * lane] = a0;
    *(float4*)&part_s[wave][1][4 * lane] = a1;
    *(float4*)&part_s[wave][2][4 * lane] = a2;
    *(float4*)&part_s[wave][3][4 * lane] = a3;
  }
  __syncthreads();
  for (int i = t; i < BPB * E; i += 512) {
    int bi = i >> 8, e = i & 255;
    float v = ipb[e];
#pragma unroll
    for (int w = 0; w < 8; ++w) v += part_s[w][bi][e];
    q_s[bi][e] = v;
  }
  __syncthreads();

  // ---- sb[b][h] = q_h · bk_h  (waves 0..3, one batch each)
  if (wave < BPB) {
#pragma unroll
    for (int h = 0; h < H; ++h) {
      float v = q_s[wave][h * DH + lane] * ipb[E + h * DH + lane];
#pragma unroll
      for (int o = 32; o; o >>= 1) v += __shfl_xor(v, o);
      if (lane == 0) sb_s[wave][h] = v;
    }
  }

  // ---- Y partials: wave -> (h = wave>>1, d-range = (wave&1)*32)
  {
    const float* Wk = ipw + (size_t)E * E;
    int h = wave >> 1, d0 = (wave & 1) * 32;
    float4 a0 = {0,0,0,0}, a1 = {0,0,0,0}, a2 = {0,0,0,0}, a3 = {0,0,0,0};
#pragma unroll
    for (int dd = 0; dd < 32; ++dd) {
      int d = d0 + dd;
      float4 w = *((const float4*)(Wk + (size_t)(h * DH + d) * E) + lane);
      float q0 = q_s[0][h * DH + d], q1 = q_s[1][h * DH + d];
      float q2 = q_s[2][h * DH + d], q3 = q_s[3][h * DH + d];
      a0.x += q0*w.x; a0.y += q0*w.y; a0.z += q0*w.z; a0.w += q0*w.w;
      a1.x += q1*w.x; a1.y += q1*w.y; a1.z += q1*w.z; a1.w += q1*w.w;
      a2.x += q2*w.x; a2.y += q2*w.y; a2.z += q2*w.z; a2.w += q2*w.w;
      a3.x += q3*w.x; a3.y += q3*w.y; a3.z += q3*w.z; a3.w += q3*w.w;
    }
    float* Yp = (float*)part_s;
    int wi = wave & 1;
    size_t o0 = (((size_t)wi * BPB + 0) * H + h) * E + 4 * lane;
    size_t o1 = (((size_t)wi * BPB + 1) * H + h) * E + 4 * lane;
    size_t o2 = (((size_t)wi * BPB + 2) * H + h) * E + 4 * lane;
    size_t o3 = (((size_t)wi * BPB + 3) * H + h) * E + 4 * lane;
    *(float4*)&Yp[o0] = a0; *(float4*)&Yp[o1] = a1;
    *(float4*)&Yp[o2] = a2; *(float4*)&Yp[o3] = a3;
  }
  __syncthreads();
  {
    float* Yp = (float*)part_s;
    for (int i = t; i < BPB * H * E; i += 512)
      ((float*)Y_s)[i] = Yp[i] + Yp[BPB * H * E + i];
  }
  __syncthreads();

  // ---- X-stream: 2 waves/batch (bb=wave>>1, wi=wave&1); 4 row-groups of 16.
  {
    int bb = wave >> 1, wi = wave & 1;
    int g = lane >> 4, sl = lane & 15;
    int sf0 = info_s[bb][0], so0 = info_s[bb][1];
    int n_f = info_s[bb][2], n = info_s[bb][3];

    // per-lane Y slices: float4 positions sl+16k  (64 VGPR)
    float4 y[H][4];
#pragma unroll
    for (int h = 0; h < H; ++h)
#pragma unroll
      for (int k = 0; k < 4; ++k)
        y[h][k] = *(const float4*)&Y_s[bb][h][4 * (sl + 16 * k)];
    float sbv[H];
#pragma unroll
    for (int h = 0; h < H; ++h) sbv[h] = sb_s[bb][h];

    float m[H] = {-3.0e38f, -3.0e38f, -3.0e38f, -3.0e38f};
    float u[H] = {0.f, 0.f, 0.f, 0.f};
    float4 acc[H][4] = {};

    int s0 = wi * 4 + g;
    float4 x[4] = {};
    if (s0 < n) {
      const float* xr = (s0 < n_f) ? face + (size_t)(sf0 + s0) * E
                                   : obj  + (size_t)(so0 + s0 - n_f) * E;
#pragma unroll
      for (int k = 0; k < 4; ++k) x[k] = ((const float4*)xr)[sl + 16 * k];
    }

    for (int s = s0; s < n; s += 8) {
      // prefetch this group's next row
      float4 xn[4] = {};
      int sn = s + 8;
      if (sn < n) {
        const float* xr = (sn < n_f) ? face + (size_t)(sf0 + sn) * E
                                     : obj  + (size_t)(so0 + sn - n_f) * E;
#pragma unroll
        for (int k = 0; k < 4; ++k) xn[k] = ((const float4*)xr)[sl + 16 * k];
      }

      float p[H];
#pragma unroll
      for (int h = 0; h < H; ++h) {
        float a = 0.f;
#pragma unroll
        for (int k = 0; k < 4; ++k)
          a += x[k].x * y[h][k].x + x[k].y * y[h][k].y +
               x[k].z * y[h][k].z + x[k].w * y[h][k].w;
        p[h] = a;
      }
#pragma unroll
      for (int off = 8; off; off >>= 1) {
#pragma unroll
        for (int h = 0; h < H; ++h) p[h] += __shfl_xor(p[h], off);
      }
#pragma unroll
      for (int h = 0; h < H; ++h) p[h] = (p[h] + sbv[h]) * 0.125f;
      if (sl == 0) {
#pragma unroll
        for (int h = 0; h < H; ++h) s_s[bb][h][s] = p[h];
      }
      // online update per head (group-uniform branches)
#pragma unroll
      for (int h = 0; h < H; ++h) {
        if (p[h] > m[h]) {
          float f = __expf(m[h] - p[h]);
#pragma unroll
          for (int k = 0; k < 4; ++k) {
            acc[h][k].x = acc[h][k].x * f + x[k].x;
            acc[h][k].y = acc[h][k].y * f + x[k].y;
            acc[h][k].z = acc[h][k].z * f + x[k].z;
            acc[h][k].w = acc[h][k].w * f + x[k].w;
          }
          u[h] = u[h] * f + 1.f;
          m[h] = p[h];
        } else {
          float e = __expf(p[h] - m[h]);
#pragma unroll
          for (int k = 0; k < 4; ++k) {
            acc[h][k].x += e * x[k].x;
            acc[h][k].y += e * x[k].y;
            acc[h][k].z += e * x[k].z;
            acc[h][k].w += e * x[k].w;
          }
          u[h] += e;
        }
      }
#pragma unroll
      for (int k = 0; k < 4; ++k) x[k] = xn[k];
    }

    // merge the 4 groups within the wave (xor 16 then 32); once per wave
#pragma unroll
    for (int off = 16; off <= 32; off <<= 1) {
#pragma unroll
      for (int h = 0; h < H; ++h) {
        float mo = __shfl_xor(m[h], off);
        float uo = __shfl_xor(u[h], off);
        float M = fmaxf(m[h], mo);
        float fs = __expf(m[h] - M), fo = __expf(mo - M);
        u[h] = fs * u[h] + fo * uo;
        m[h] = M;
#pragma unroll
        for (int k = 0; k < 4; ++k) {
          float ax = __shfl_xor(acc[h][k].x, off);
          float ay = __shfl_xor(acc[h][k].y, off);
          float az = __shfl_xor(acc[h][k].z, off);
          float aw = __shfl_xor(acc[h][k].w, off);
          acc[h][k].x = fs * acc[h][k].x + fo * ax;
          acc[h][k].y = fs * acc[h][k].y + fo * ay;
          acc[h][k].z = fs * acc[h][k].z + fo * az;
          acc[h][k].w = fs * acc[h][k].w + fo * aw;
        }
      }
    }
    if (g == 0) {
#pragma unroll
      for (int h = 0; h < H; ++h)
#pragma unroll
        for (int k = 0; k < 4; ++k)
          *(float4*)&Zp_s[bb][wi][h][4 * (sl + 16 * k)] = acc[h][k];
    }
    if (lane == 0) {
#pragma unroll
      for (int h = 0; h < H; ++h) {
        mw_s[bb][wi][h] = m[h];
        su_s[bb][wi][h] = u[h];
      }
    }
  }
  __syncthreads();

  // ---- merge Z (2 wave-partials) ; normalize
  for (int i = t; i < BPB * H * E; i += 512) {
    int bi = i >> 10, rem = i & 1023, h = rem >> 8, e = rem & 255;
    float z = 0.f;
    if (info_s[bi][3] > 0) {
      float ma = mw_s[bi][0][h], mb = mw_s[bi][1][h];
      float M = fmaxf(ma, mb);
      float fa = __expf(ma - M), fb = __expf(mb - M);
      float inv = 1.0f / (fa * su_s[bi][0][h] + fb * su_s[bi][1][h]);
      z = (fa * Zp_s[bi][0][h][e] + fb * Zp_s[bi][1][h][e]) * inv;
    }
    ((float*)Z_s)[i] = z;
  }
  // ---- attnw
  for (int i = t; i < BPB * L; i += 512) {
    int bi = i / L, s = i - bi * L;
    int n = info_s[bi][3];
    float v;
    if (n == 0) v = 1.0f / L;
    else if (s < n) {
      v = 0.f;
#pragma unroll
      for (int h = 0; h < H; ++h) {
        float ma = mw_s[bi][0][h], mb = mw_s[bi][1][h];
        float M = fmaxf(ma, mb);
        float fa = __expf(ma - M), fb = __expf(mb - M);
        float inv = 1.0f / (fa * su_s[bi][0][h] + fb * su_s[bi][1][h]);
        v += __expf(s_s[bi][h][s] - M) * inv;
      }
      v *= 0.25f;
    } else v = 0.f;
    attnw[(size_t)(b0 + bi) * L + s] = v;
  }
  __syncthreads();

  // ---- ctx partials: wave covers j-range 32; head(lane) = lane>>4
  {
    const float4* W4 = (const float4*)WvT + lane;
    int j0 = wave * 32, hoff = (lane >> 4) * E;
    float4 a0 = {0,0,0,0}, a1 = {0,0,0,0}, a2 = {0,0,0,0}, a3 = {0,0,0,0};
#pragma unroll
    for (int jj = 0; jj < 32; ++jj) {
      int j = j0 + jj;
      float4 w = W4[(size_t)j * 64];
      float z0 = ((float*)Z_s[0])[hoff + j];
      float z1 = ((float*)Z_s[1])[hoff + j];
      float z2 = ((float*)Z_s[2])[hoff + j];
      float z3 = ((float*)Z_s[3])[hoff + j];
      a0.x += z0*w.x; a0.y += z0*w.y; a0.z += z0*w.z; a0.w += z0*w.w;
      a1.x += z1*w.x; a1.y += z1*w.y; a1.z += z1*w.z; a1.w += z1*w.w;
      a2.x += z2*w.x; a2.y += z2*w.y; a2.z += z2*w.z; a2.w += z2*w.w;
      a3.x += z3*w.x; a3.y += z3*w.y; a3.z += z3*w.z; a3.w += z3*w.w;
    }
    *(float4*)&part_s[wave][0][4 * lane] = a0;
    *(float4*)&part_s[wave][1][4 * lane] = a1;
    *(float4*)&part_s[wave][2][4 * lane] = a2;
    *(float4*)&part_s[wave][3][4 * lane] = a3;
  }
  __syncthreads();
  for (int i = t; i < BPB * E; i += 512) {
    int bi = i >> 8, e = i & 255;
    float v = ipb[2 * E + e];
#pragma unroll
    for (int w = 0; w < 8; ++w) v += part_s[w][bi][e];
    ctx_s[bi][e] = v;
  }
  __syncthreads();

  // ---- out-proj partials
  {
    const float4* W4 = (const float4*)WoT + lane;
    int j0 = wave * 32;
    float4 a0 = {0,0,0,0}, a1 = {0,0,0,0}, a2 = {0,0,0,0}, a3 = {0,0,0,0};
#pragma unroll
    for (int jj = 0; jj < 32; ++jj) {
      int j = j0 + jj;
      float4 w = W4[(size_t)j * 64];
      float c0 = ctx_s[0][j], c1 = ctx_s[1][j], c2 = ctx_s[2][j], c3 = ctx_s[3][j];
      a0.x += c0*w.x; a0.y += c0*w.y; a0.z += c0*w.z; a0.w += c0*w.w;
      a1.x += c1*w.x; a1.y += c1*w.y; a1.z += c1*w.z; a1.w += c1*w.w;
      a2.x += c2*w.x; a2.y += c2*w.y; a2.z += c2*w.z; a2.w += c2*w.w;
      a3.x += c3*w.x; a3.y += c3*w.y; a3.z += c3*w.z; a3.w += c3*w.w;
    }
    *(float4*)&part_s[wave][0][4 * lane] = a0;
    *(float4*)&part_s[wave][1][4 * lane] = a1;
    *(float4*)&part_s[wave][2][4 * lane] = a2;
    *(float4*)&part_s[wave][3][4 * lane] = a3;
  }
  __syncthreads();
  for (int i = t; i < BPB * E; i += 512) {
    int bi = i >> 8, e = i & 255;
    float v = opb[e] + sc_s[bi][e];
#pragma unroll
    for (int w = 0; w < 8; ++w) v += part_s[w][bi][e];
    q_s[bi][e] = v;
  }
  __syncthreads();

  // ---- LayerNorm: waves 0..3, one batch each (in-wave over 256 values)
  if (wave < BPB) {
    float v0 = q_s[wave][lane], v1 = q_s[wave][lane + 64],
          v2 = q_s[wave][lane + 128], v3 = q_s[wave][lane + 192];
    float s1 = v0 + v1 + v2 + v3;
#pragma unroll
    for (int o = 32; o; o >>= 1) s1 += __shfl_xor(s1, o);
    float mu = s1 * (1.0f / E);
    float d0 = v0 - mu, d1 = v1 - mu, d2 = v2 - mu, d3 = v3 - mu;
    float s2 = d0*d0 + d1*d1 + d2*d2 + d3*d3;
#pragma unroll
    for (int o = 32; o; o >>= 1) s2 += __shfl_xor(s2, o);
    float inv = 1.0f / sqrtf(s2 * (1.0f / E) + 1e-5f);
    size_t base = (size_t)(b0 + wave) * E;
    fusedO[base + lane      ] = d0 * inv * gamma[lane      ] + beta[lane      ];
    fusedO[base + lane +  64] = d1 * inv * gamma[lane +  64] + beta[lane +  64];
    fusedO[base + lane + 128] = d2 * inv * gamma[lane + 128] + beta[lane + 128];
    fusedO[base + lane + 192] = d3 * inv * gamma[lane + 192] + beta[lane + 192];
  }
}

// ---------------------------------------------------------------------------
extern "C" void kernel_launch(void* const* d_in, const int* in_sizes, int n_in,
                              void* d_out, int out_size, void* d_ws, size_t ws_size,
                              hipStream_t stream) {
  const float* scene = (const float*)d_in[0];
  const float* face  = (const float*)d_in[1];
  const float* obj   = (const float*)d_in[2];
  const int*   fb    = (const int*)d_in[3];
  const int*   ob    = (const int*)d_in[4];
  const float* ipw   = (const float*)d_in[5];
  const float* ipb   = (const float*)d_in[6];
  const float* opw   = (const float*)d_in[7];
  const float* opb   = (const float*)d_in[8];
  const float* gam   = (const float*)d_in[9];
  const float* bet   = (const float*)d_in[10];

  float* fused = (float*)d_out;
  float* attnw = fused + (size_t)B * E;

  // ws: starts (16KB) | WT (768KB)
  int* start_f = (int*)d_ws;
  int* start_o = start_f + (B + 1);
  float* WT   = (float*)((char*)d_ws + (16 << 10));
  float* WqT = WT;
  float* WvT = WT + (size_t)E * E;
  float* WoT = WT + (size_t)2 * E * E;

  prep_kernel<<<197, 256, 0, stream>>>(fb, ob, start_f, start_o, ipw, opw, WT);
  fused_kernel<<<B / BPB, 512, 0, stream>>>(scene, face, obj, ipw, ipb,
                                            WqT, WvT, WoT, opb, gam, bet,
                                            start_f, start_o, fused, attnw);
}